// Round 1
// baseline (1154.366 us; speedup 1.0000x reference)
//
#include <hip/hip_runtime.h>
#include <math.h>

#define HH 480
#define WW 640
#define NPIX (HH*WW)
#define NACC 29           // 21 (A upper tri) + 6 (b) + 1 (sum r_icp^2) + 1 (sum r_rgb^2)
#define TPB 256
#define MAPBLK (NPIX/TPB) // 1200, exact

// d_ws float layout:
// [0..5] x | [6] conv | [7] cost | [8..16] R row-major | [17..19] t | [32 ..] partials[MAPBLK][NACC]
#define WS_PART 32

__device__ __forceinline__ float gradu(const float* g, int v, int u) {
    const float* row = g + v * WW;
    if (u == 0)      return row[1] - row[0];
    if (u == WW - 1) return row[WW - 1] - row[WW - 2];
    return 0.5f * (row[u + 1] - row[u - 1]);
}
__device__ __forceinline__ float gradv(const float* g, int v, int u) {
    if (v == 0)      return g[WW + u] - g[u];
    if (v == HH - 1) return g[(HH - 1) * WW + u] - g[(HH - 2) * WW + u];
    return 0.5f * (g[(v + 1) * WW + u] - g[(v - 1) * WW + u]);
}

__device__ void exp_se3_f32(const float* xi, float* T) {
    float v0 = xi[0], v1 = xi[1], v2 = xi[2];
    float w0 = xi[3], w1 = xi[4], w2 = xi[5];
    float th2 = w0 * w0 + w1 * w1 + w2 * w2;
    float th = sqrtf(th2);
    bool small = th < 1e-8f;
    float ths = small ? 1.0f : th;
    float A = small ? (1.0f - th2 / 6.0f) : (sinf(ths) / ths);
    float B = small ? (0.5f - th2 / 24.0f) : ((1.0f - cosf(ths)) / (ths * ths));
    float C = small ? (1.0f / 6.0f - th2 / 120.0f) : ((ths - sinf(ths)) / (ths * ths * ths));
    float Wx[9] = { 0.f, -w2,  w1,
                    w2,  0.f, -w0,
                   -w1,  w0,  0.f };
    float W2[9];
    #pragma unroll
    for (int i = 0; i < 3; i++)
        #pragma unroll
        for (int j = 0; j < 3; j++) {
            float s = 0.f;
            #pragma unroll
            for (int k = 0; k < 3; k++) s += Wx[i * 3 + k] * Wx[k * 3 + j];
            W2[i * 3 + j] = s;
        }
    float R[9], V[9];
    #pragma unroll
    for (int i = 0; i < 9; i++) {
        float id = (i == 0 || i == 4 || i == 8) ? 1.0f : 0.0f;
        R[i] = id + A * Wx[i] + B * W2[i];
        V[i] = id + B * Wx[i] + C * W2[i];
    }
    float t0 = V[0] * v0 + V[1] * v1 + V[2] * v2;
    float t1 = V[3] * v0 + V[4] * v1 + V[5] * v2;
    float t2 = V[6] * v0 + V[7] * v1 + V[8] * v2;
    T[0] = R[0]; T[1] = R[1]; T[2]  = R[2]; T[3]  = t0;
    T[4] = R[3]; T[5] = R[4]; T[6]  = R[5]; T[7]  = t1;
    T[8] = R[6]; T[9] = R[7]; T[10] = R[8]; T[11] = t2;
    T[12] = 0.f; T[13] = 0.f; T[14] = 0.f; T[15] = 1.f;
}

__global__ void init_state(float* ws) {
    if (threadIdx.x == 0) {
        #pragma unroll
        for (int i = 0; i < 8; i++) ws[i] = 0.f;
        ws[8]  = 1.f; ws[9]  = 0.f; ws[10] = 0.f;
        ws[11] = 0.f; ws[12] = 1.f; ws[13] = 0.f;
        ws[14] = 0.f; ws[15] = 0.f; ws[16] = 1.f;
        ws[17] = 0.f; ws[18] = 0.f; ws[19] = 0.f;
    }
}

__device__ __forceinline__ void accum_point(float* acc, const float* J, float r, float w, int costslot) {
    int k = 0;
    #pragma unroll
    for (int i = 0; i < 6; i++) {
        #pragma unroll
        for (int j = i; j < 6; j++) { acc[k] += w * (J[i] * J[j]); k++; }
        acc[21 + i] += w * (J[i] * r);
    }
    acc[costslot] += r * r;
}

__global__ __launch_bounds__(TPB) void map_reduce(
    const float* __restrict__ depth_ref,
    const float* __restrict__ normals_ref,
    const float* __restrict__ gray_ref,
    const float* __restrict__ gray_target,
    const float* __restrict__ points_target,
    const float* __restrict__ normals_target,
    const float* __restrict__ K,
    float* __restrict__ ws)
{
    const float fx = K[0], cx = K[2], fy = K[4], cy = K[5];
    const float R00 = ws[8],  R01 = ws[9],  R02 = ws[10];
    const float R10 = ws[11], R11 = ws[12], R12 = ws[13];
    const float R20 = ws[14], R21 = ws[15], R22 = ws[16];
    const float t0 = ws[17], t1 = ws[18], t2 = ws[19];

    int p = blockIdx.x * TPB + threadIdx.x;
    int vv = p / WW;
    int uu = p - vv * WW;

    float acc[NACC];
    #pragma unroll
    for (int i = 0; i < NACC; i++) acc[i] = 0.f;

    float Z = depth_ref[p];
    float Px = ((float)uu - cx) / fx * Z;
    float Py = ((float)vv - cy) / fy * Z;
    float Pz = Z;
    float Ptx = R00 * Px + R01 * Py + R02 * Pz + t0;
    float Pty = R10 * Px + R11 * Py + R12 * Pz + t1;
    float Ptz = R20 * Px + R21 * Py + R22 * Pz + t2;
    bool okz = Ptz > 1e-6f;
    float Zs = okz ? Ptz : 1.0f;
    float u = fx * Ptx / Zs + cx;
    float v = fy * Pty / Zs + cy;
    bool inb = okz && (u >= 0.f) && (u <= (float)(WW - 1)) && (v >= 0.f) && (v <= (float)(HH - 1));

    if (inb) {
        // ---- ICP term (nearest-neighbor projective association) ----
        int ui = (int)rintf(u); ui = ui < 0 ? 0 : (ui > WW - 1 ? WW - 1 : ui);
        int vi = (int)rintf(v); vi = vi < 0 ? 0 : (vi > HH - 1 ? HH - 1 : vi);
        int qi = (vi * WW + ui) * 3;
        float qx = points_target[qi], qy = points_target[qi + 1], qz = points_target[qi + 2];
        float nqx = normals_target[qi], nqy = normals_target[qi + 1], nqz = normals_target[qi + 2];
        float dx = Ptx - qx, dy = Pty - qy, dz = Ptz - qz;
        float nr0 = normals_ref[3 * p], nr1 = normals_ref[3 * p + 1], nr2 = normals_ref[3 * p + 2];
        float nrx = R00 * nr0 + R01 * nr1 + R02 * nr2;
        float nry = R10 * nr0 + R11 * nr1 + R12 * nr2;
        float nrz = R20 * nr0 + R21 * nr1 + R22 * nr2;
        const float DIST2 = (float)((200.0 / 15.0) * (200.0 / 15.0));
        if ((dx * dx + dy * dy + dz * dz) < DIST2 &&
            (nrx * nqx + nry * nqy + nrz * nqz) > 0.94f) {
            float r = nqx * dx + nqy * dy + nqz * dz;
            float J[6] = { nqx, nqy, nqz,
                           Pty * nqz - Ptz * nqy,
                           Ptz * nqx - Ptx * nqz,
                           Ptx * nqy - Pty * nqx };
            accum_point(acc, J, r, 10.0f, 27);
        }
        // ---- RGB (photometric) term ----
        float u0f = floorf(u), v0f = floorf(v);
        float du = u - u0f, dv = v - v0f;
        int u0 = (int)u0f; u0 = u0 < 0 ? 0 : (u0 > WW - 1 ? WW - 1 : u0);
        int u1 = (u0 + 1 > WW - 1) ? WW - 1 : u0 + 1;
        int v0 = (int)v0f; v0 = v0 < 0 ? 0 : (v0 > HH - 1 ? HH - 1 : v0);
        int v1 = (v0 + 1 > HH - 1) ? HH - 1 : v0 + 1;
        const float* g = gray_target;
        float I00 = g[v0 * WW + u0], I01 = g[v0 * WW + u1];
        float I10 = g[v1 * WW + u0], I11 = g[v1 * WW + u1];
        float It  = (I00 * (1.f - du) + I01 * du) * (1.f - dv) + (I10 * (1.f - du) + I11 * du) * dv;
        float gx00 = gradu(g, v0, u0), gx01 = gradu(g, v0, u1);
        float gx10 = gradu(g, v1, u0), gx11 = gradu(g, v1, u1);
        float gxs = (gx00 * (1.f - du) + gx01 * du) * (1.f - dv) + (gx10 * (1.f - du) + gx11 * du) * dv;
        float gy00 = gradv(g, v0, u0), gy01 = gradv(g, v0, u1);
        float gy10 = gradv(g, v1, u0), gy11 = gradv(g, v1, u1);
        float gys = (gy00 * (1.f - du) + gy01 * du) * (1.f - dv) + (gy10 * (1.f - du) + gy11 * du) * dv;
        float rr = It - gray_ref[p];
        float gpx = gxs * fx / Zs;
        float gpy = gys * fy / Zs;
        float gpz = -(gxs * fx * Ptx + gys * fy * Pty) / (Zs * Zs);
        float J[6] = { gpx, gpy, gpz,
                       Pty * gpz - Ptz * gpy,
                       Ptz * gpx - Ptx * gpz,
                       Ptx * gpy - Pty * gpx };
        accum_point(acc, J, rr, 1.0f, 28);
    }

    // ---- deterministic in-block reduction: wave shuffle -> LDS -> block partial ----
    #pragma unroll
    for (int q = 0; q < NACC; q++) {
        float vq = acc[q];
        #pragma unroll
        for (int off = 32; off >= 1; off >>= 1) vq += __shfl_xor(vq, off);
        acc[q] = vq;
    }
    __shared__ float lds[4][NACC];
    int wave = threadIdx.x >> 6;
    int lane = threadIdx.x & 63;
    if (lane == 0) {
        #pragma unroll
        for (int q = 0; q < NACC; q++) lds[wave][q] = acc[q];
    }
    __syncthreads();
    if (threadIdx.x < NACC) {
        int q = threadIdx.x;
        float s = lds[0][q] + lds[1][q] + lds[2][q] + lds[3][q];
        ws[WS_PART + blockIdx.x * NACC + q] = s;
    }
}

__global__ __launch_bounds__(TPB) void solve_update(float* __restrict__ ws,
                                                    float* __restrict__ out,
                                                    int final_iter)
{
    __shared__ double part[NACC * 8];
    __shared__ double sums[NACC];
    int tid = threadIdx.x;
    if (tid < NACC * 8) {
        int q = tid >> 3, s = tid & 7;
        double sm = 0.0;
        for (int b = s; b < MAPBLK; b += 8) sm += (double)ws[WS_PART + b * NACC + q];
        part[tid] = sm;
    }
    __syncthreads();
    if (tid < NACC) {
        double sm = 0.0;
        #pragma unroll
        for (int s = 0; s < 8; s++) sm += part[tid * 8 + s];
        sums[tid] = sm;
    }
    __syncthreads();
    if (tid == 0) {
        double M[6][7];
        int k = 0;
        for (int i = 0; i < 6; i++)
            for (int j = i; j < 6; j++) { M[i][j] = sums[k]; M[j][i] = sums[k]; k++; }
        for (int i = 0; i < 6; i++) { M[i][6] = sums[21 + i]; M[i][i] += 1e-9; }
        double new_cost = 10.0 * sums[27] / (double)NPIX + sums[28] / (double)NPIX;

        // 6x6 Gaussian elimination with partial pivoting (f64)
        for (int c = 0; c < 6; c++) {
            int piv = c; double mx = fabs(M[c][c]);
            for (int r2 = c + 1; r2 < 6; r2++) {
                double a = fabs(M[r2][c]);
                if (a > mx) { mx = a; piv = r2; }
            }
            if (piv != c)
                for (int j2 = 0; j2 < 7; j2++) { double tmp = M[c][j2]; M[c][j2] = M[piv][j2]; M[piv][j2] = tmp; }
            double inv = 1.0 / M[c][c];
            for (int r2 = c + 1; r2 < 6; r2++) {
                double f = M[r2][c] * inv;
                for (int j2 = c; j2 < 7; j2++) M[r2][j2] -= f * M[c][j2];
            }
        }
        double x0[6];
        for (int i = 5; i >= 0; i--) {
            double s = M[i][6];
            for (int j = i + 1; j < 6; j++) s -= M[i][j] * x0[j];
            x0[i] = s / M[i][i];
        }

        double nx0 = 0.0, nx = 0.0;
        float xf[6];
        for (int i = 0; i < 6; i++) {
            xf[i] = ws[i];
            nx0 += x0[i] * x0[i];
            nx  += (double)xf[i] * (double)xf[i];
        }
        nx0 = sqrt(nx0); nx = sqrt(nx);
        bool convold = (ws[6] != 0.f);
        bool c2 = convold || (new_cost < 1e-3) || (nx0 < 1e-8 * (1e-8 + nx));
        float xn[6];
        for (int i = 0; i < 6; i++)
            xn[i] = c2 ? xf[i] : (float)((double)xf[i] - x0[i]);
        for (int i = 0; i < 6; i++) ws[i] = xn[i];
        ws[6] = c2 ? 1.f : 0.f;
        if (!convold) ws[7] = (float)new_cost;

        float T[16];
        exp_se3_f32(xn, T);
        ws[8]  = T[0]; ws[9]  = T[1]; ws[10] = T[2];
        ws[11] = T[4]; ws[12] = T[5]; ws[13] = T[6];
        ws[14] = T[8]; ws[15] = T[9]; ws[16] = T[10];
        ws[17] = T[3]; ws[18] = T[7]; ws[19] = T[11];

        if (final_iter) {
            for (int i = 0; i < 16; i++) out[i] = T[i];
            out[16] = ws[7];
        }
    }
}

extern "C" void kernel_launch(void* const* d_in, const int* in_sizes, int n_in,
                              void* d_out, int out_size, void* d_ws, size_t ws_size,
                              hipStream_t stream) {
    const float* depth_ref      = (const float*)d_in[0];
    const float* normals_ref    = (const float*)d_in[1];
    const float* gray_ref       = (const float*)d_in[2];
    const float* gray_target    = (const float*)d_in[3];
    const float* points_target  = (const float*)d_in[4];
    const float* normals_target = (const float*)d_in[5];
    const float* K              = (const float*)d_in[6];
    float* ws  = (float*)d_ws;
    float* out = (float*)d_out;

    hipLaunchKernelGGL(init_state, dim3(1), dim3(64), 0, stream, ws);
    for (int it = 0; it < 20; ++it) {
        hipLaunchKernelGGL(map_reduce, dim3(MAPBLK), dim3(TPB), 0, stream,
                           depth_ref, normals_ref, gray_ref, gray_target,
                           points_target, normals_target, K, ws);
        hipLaunchKernelGGL(solve_update, dim3(1), dim3(TPB), 0, stream,
                           ws, out, (it == 19) ? 1 : 0);
    }
}

// Round 2
// 433.732 us; speedup vs baseline: 2.6615x; 2.6615x over previous
//
#include <hip/hip_runtime.h>
#include <math.h>

#define HH 480
#define WW 640
#define NPIX (HH*WW)
#define NACC 29           // 21 (A upper tri) + 6 (b) + 1 (sum r_icp^2) + 1 (sum r_rgb^2)
#define TPB 256
#define PXPT 4
#define MB (NPIX/(TPB*PXPT)) // 300 map blocks, exact

// d_ws float layout:
// [0..5] x | [6] conv | [7] cost | [8..16] R row-major | [17..19] t
// [32 ..] partials TRANSPOSED: part[q*MB + block], q in [0,NACC)
#define WS_PART 32

__device__ __forceinline__ float gradu(const float* g, int v, int u) {
    const float* row = g + v * WW;
    if (u == 0)      return row[1] - row[0];
    if (u == WW - 1) return row[WW - 1] - row[WW - 2];
    return 0.5f * (row[u + 1] - row[u - 1]);
}
__device__ __forceinline__ float gradv(const float* g, int v, int u) {
    if (v == 0)      return g[WW + u] - g[u];
    if (v == HH - 1) return g[(HH - 1) * WW + u] - g[(HH - 2) * WW + u];
    return 0.5f * (g[(v + 1) * WW + u] - g[(v - 1) * WW + u]);
}

__device__ void exp_se3_f32(const float* xi, float* T) {
    float v0 = xi[0], v1 = xi[1], v2 = xi[2];
    float w0 = xi[3], w1 = xi[4], w2 = xi[5];
    float th2 = w0 * w0 + w1 * w1 + w2 * w2;
    float th = sqrtf(th2);
    bool small = th < 1e-8f;
    float ths = small ? 1.0f : th;
    float A = small ? (1.0f - th2 / 6.0f) : (sinf(ths) / ths);
    float B = small ? (0.5f - th2 / 24.0f) : ((1.0f - cosf(ths)) / (ths * ths));
    float C = small ? (1.0f / 6.0f - th2 / 120.0f) : ((ths - sinf(ths)) / (ths * ths * ths));
    float Wx[9] = { 0.f, -w2,  w1,
                    w2,  0.f, -w0,
                   -w1,  w0,  0.f };
    float W2[9];
    #pragma unroll
    for (int i = 0; i < 3; i++)
        #pragma unroll
        for (int j = 0; j < 3; j++) {
            float s = 0.f;
            #pragma unroll
            for (int k = 0; k < 3; k++) s += Wx[i * 3 + k] * Wx[k * 3 + j];
            W2[i * 3 + j] = s;
        }
    float R[9], V[9];
    #pragma unroll
    for (int i = 0; i < 9; i++) {
        float id = (i == 0 || i == 4 || i == 8) ? 1.0f : 0.0f;
        R[i] = id + A * Wx[i] + B * W2[i];
        V[i] = id + B * Wx[i] + C * W2[i];
    }
    float t0 = V[0] * v0 + V[1] * v1 + V[2] * v2;
    float t1 = V[3] * v0 + V[4] * v1 + V[5] * v2;
    float t2 = V[6] * v0 + V[7] * v1 + V[8] * v2;
    T[0] = R[0]; T[1] = R[1]; T[2]  = R[2]; T[3]  = t0;
    T[4] = R[3]; T[5] = R[4]; T[6]  = R[5]; T[7]  = t1;
    T[8] = R[6]; T[9] = R[7]; T[10] = R[8]; T[11] = t2;
    T[12] = 0.f; T[13] = 0.f; T[14] = 0.f; T[15] = 1.f;
}

__global__ void init_state(float* ws) {
    if (threadIdx.x == 0) {
        #pragma unroll
        for (int i = 0; i < 8; i++) ws[i] = 0.f;
        ws[8]  = 1.f; ws[9]  = 0.f; ws[10] = 0.f;
        ws[11] = 0.f; ws[12] = 1.f; ws[13] = 0.f;
        ws[14] = 0.f; ws[15] = 0.f; ws[16] = 1.f;
        ws[17] = 0.f; ws[18] = 0.f; ws[19] = 0.f;
    }
}

__device__ __forceinline__ void accum_point(float* acc, const float* J, float r, float w, int costslot) {
    int k = 0;
    #pragma unroll
    for (int i = 0; i < 6; i++) {
        #pragma unroll
        for (int j = i; j < 6; j++) { acc[k] += w * (J[i] * J[j]); k++; }
        acc[21 + i] += w * (J[i] * r);
    }
    acc[costslot] += r * r;
}

__device__ __forceinline__ void process_pixel(
    int p, float fx, float fy, float cx, float cy,
    float R00, float R01, float R02, float R10, float R11, float R12,
    float R20, float R21, float R22, float t0, float t1, float t2,
    const float* __restrict__ depth_ref, const float* __restrict__ normals_ref,
    const float* __restrict__ gray_ref, const float* __restrict__ gray_target,
    const float* __restrict__ points_target, const float* __restrict__ normals_target,
    float* acc)
{
    int vv = p / WW;
    int uu = p - vv * WW;

    float Z = depth_ref[p];
    float Px = ((float)uu - cx) / fx * Z;
    float Py = ((float)vv - cy) / fy * Z;
    float Pz = Z;
    float Ptx = R00 * Px + R01 * Py + R02 * Pz + t0;
    float Pty = R10 * Px + R11 * Py + R12 * Pz + t1;
    float Ptz = R20 * Px + R21 * Py + R22 * Pz + t2;
    bool okz = Ptz > 1e-6f;
    float Zs = okz ? Ptz : 1.0f;
    float u = fx * Ptx / Zs + cx;
    float v = fy * Pty / Zs + cy;
    bool inb = okz && (u >= 0.f) && (u <= (float)(WW - 1)) && (v >= 0.f) && (v <= (float)(HH - 1));
    if (!inb) return;

    // ---- ICP term (nearest-neighbor projective association) ----
    int ui = (int)rintf(u); ui = ui < 0 ? 0 : (ui > WW - 1 ? WW - 1 : ui);
    int vi = (int)rintf(v); vi = vi < 0 ? 0 : (vi > HH - 1 ? HH - 1 : vi);
    int qi = (vi * WW + ui) * 3;
    float qx = points_target[qi], qy = points_target[qi + 1], qz = points_target[qi + 2];
    float nqx = normals_target[qi], nqy = normals_target[qi + 1], nqz = normals_target[qi + 2];
    float dx = Ptx - qx, dy = Pty - qy, dz = Ptz - qz;
    float nr0 = normals_ref[3 * p], nr1 = normals_ref[3 * p + 1], nr2 = normals_ref[3 * p + 2];
    float nrx = R00 * nr0 + R01 * nr1 + R02 * nr2;
    float nry = R10 * nr0 + R11 * nr1 + R12 * nr2;
    float nrz = R20 * nr0 + R21 * nr1 + R22 * nr2;
    const float DIST2 = (float)((200.0 / 15.0) * (200.0 / 15.0));
    if ((dx * dx + dy * dy + dz * dz) < DIST2 &&
        (nrx * nqx + nry * nqy + nrz * nqz) > 0.94f) {
        float r = nqx * dx + nqy * dy + nqz * dz;
        float J[6] = { nqx, nqy, nqz,
                       Pty * nqz - Ptz * nqy,
                       Ptz * nqx - Ptx * nqz,
                       Ptx * nqy - Pty * nqx };
        accum_point(acc, J, r, 10.0f, 27);
    }
    // ---- RGB (photometric) term ----
    float u0f = floorf(u), v0f = floorf(v);
    float du = u - u0f, dv = v - v0f;
    int u0 = (int)u0f; u0 = u0 < 0 ? 0 : (u0 > WW - 1 ? WW - 1 : u0);
    int u1 = (u0 + 1 > WW - 1) ? WW - 1 : u0 + 1;
    int v0 = (int)v0f; v0 = v0 < 0 ? 0 : (v0 > HH - 1 ? HH - 1 : v0);
    int v1 = (v0 + 1 > HH - 1) ? HH - 1 : v0 + 1;
    const float* g = gray_target;
    float I00 = g[v0 * WW + u0], I01 = g[v0 * WW + u1];
    float I10 = g[v1 * WW + u0], I11 = g[v1 * WW + u1];
    float It  = (I00 * (1.f - du) + I01 * du) * (1.f - dv) + (I10 * (1.f - du) + I11 * du) * dv;
    float gx00 = gradu(g, v0, u0), gx01 = gradu(g, v0, u1);
    float gx10 = gradu(g, v1, u0), gx11 = gradu(g, v1, u1);
    float gxs = (gx00 * (1.f - du) + gx01 * du) * (1.f - dv) + (gx10 * (1.f - du) + gx11 * du) * dv;
    float gy00 = gradv(g, v0, u0), gy01 = gradv(g, v0, u1);
    float gy10 = gradv(g, v1, u0), gy11 = gradv(g, v1, u1);
    float gys = (gy00 * (1.f - du) + gy01 * du) * (1.f - dv) + (gy10 * (1.f - du) + gy11 * du) * dv;
    float rr = It - gray_ref[p];
    float gpx = gxs * fx / Zs;
    float gpy = gys * fy / Zs;
    float gpz = -(gxs * fx * Ptx + gys * fy * Pty) / (Zs * Zs);
    float J[6] = { gpx, gpy, gpz,
                   Pty * gpz - Ptz * gpy,
                   Ptz * gpx - Ptx * gpz,
                   Ptx * gpy - Pty * gpx };
    accum_point(acc, J, rr, 1.0f, 28);
}

__global__ __launch_bounds__(TPB) void map_reduce(
    const float* __restrict__ depth_ref,
    const float* __restrict__ normals_ref,
    const float* __restrict__ gray_ref,
    const float* __restrict__ gray_target,
    const float* __restrict__ points_target,
    const float* __restrict__ normals_target,
    const float* __restrict__ K,
    float* __restrict__ ws)
{
    const float fx = K[0], cx = K[2], fy = K[4], cy = K[5];
    const float R00 = ws[8],  R01 = ws[9],  R02 = ws[10];
    const float R10 = ws[11], R11 = ws[12], R12 = ws[13];
    const float R20 = ws[14], R21 = ws[15], R22 = ws[16];
    const float t0 = ws[17], t1 = ws[18], t2 = ws[19];

    float acc[NACC];
    #pragma unroll
    for (int i = 0; i < NACC; i++) acc[i] = 0.f;

    int pbase = blockIdx.x * (TPB * PXPT) + threadIdx.x;
    #pragma unroll
    for (int k = 0; k < PXPT; k++) {
        process_pixel(pbase + k * TPB, fx, fy, cx, cy,
                      R00, R01, R02, R10, R11, R12, R20, R21, R22, t0, t1, t2,
                      depth_ref, normals_ref, gray_ref, gray_target,
                      points_target, normals_target, acc);
    }

    // ---- deterministic in-block reduction: wave shuffle -> LDS -> block partial ----
    #pragma unroll
    for (int q = 0; q < NACC; q++) {
        float vq = acc[q];
        #pragma unroll
        for (int off = 32; off >= 1; off >>= 1) vq += __shfl_xor(vq, off);
        acc[q] = vq;
    }
    __shared__ float lds[4][NACC];
    int wave = threadIdx.x >> 6;
    int lane = threadIdx.x & 63;
    if (lane == 0) {
        #pragma unroll
        for (int q = 0; q < NACC; q++) lds[wave][q] = acc[q];
    }
    __syncthreads();
    if (threadIdx.x < NACC) {
        int q = threadIdx.x;
        float s = lds[0][q] + lds[1][q] + lds[2][q] + lds[3][q];
        ws[WS_PART + q * MB + blockIdx.x] = s;   // transposed: [q][block]
    }
}

__global__ __launch_bounds__(TPB) void solve_update(float* __restrict__ ws,
                                                    float* __restrict__ out,
                                                    int final_iter)
{
    __shared__ double part8[NACC * 8];
    __shared__ double sums[NACC];
    int tid = threadIdx.x;
    const float* part = ws + WS_PART;
    // Stage 1: 29 q * 8 threads; each thread reads a CONTIGUOUS chunk of its
    // q-row with 4 independent accumulators so loads pipeline.
    if (tid < NACC * 8) {
        int q = tid >> 3, s = tid & 7;
        const int CH = (MB + 7) / 8;          // 38
        int lo = s * CH;
        int hi = lo + CH; if (hi > MB) hi = MB;
        const float* row = part + q * MB;
        double a0 = 0.0, a1 = 0.0, a2 = 0.0, a3 = 0.0;
        int i = lo;
        for (; i + 4 <= hi; i += 4) {
            a0 += (double)row[i];
            a1 += (double)row[i + 1];
            a2 += (double)row[i + 2];
            a3 += (double)row[i + 3];
        }
        for (; i < hi; i++) a0 += (double)row[i];
        part8[tid] = ((a0 + a1) + (a2 + a3));
    }
    __syncthreads();
    if (tid < NACC) {
        double sm = 0.0;
        #pragma unroll
        for (int s = 0; s < 8; s++) sm += part8[tid * 8 + s];
        sums[tid] = sm;
    }
    __syncthreads();
    if (tid == 0) {
        double M[6][7];
        int k = 0;
        for (int i = 0; i < 6; i++)
            for (int j = i; j < 6; j++) { M[i][j] = sums[k]; M[j][i] = sums[k]; k++; }
        for (int i = 0; i < 6; i++) { M[i][6] = sums[21 + i]; M[i][i] += 1e-9; }
        double new_cost = 10.0 * sums[27] / (double)NPIX + sums[28] / (double)NPIX;

        // 6x6 Gaussian elimination with partial pivoting (f64)
        for (int c = 0; c < 6; c++) {
            int piv = c; double mx = fabs(M[c][c]);
            for (int r2 = c + 1; r2 < 6; r2++) {
                double a = fabs(M[r2][c]);
                if (a > mx) { mx = a; piv = r2; }
            }
            if (piv != c)
                for (int j2 = 0; j2 < 7; j2++) { double tmp = M[c][j2]; M[c][j2] = M[piv][j2]; M[piv][j2] = tmp; }
            double inv = 1.0 / M[c][c];
            for (int r2 = c + 1; r2 < 6; r2++) {
                double f = M[r2][c] * inv;
                for (int j2 = c; j2 < 7; j2++) M[r2][j2] -= f * M[c][j2];
            }
        }
        double x0[6];
        for (int i = 5; i >= 0; i--) {
            double s = M[i][6];
            for (int j = i + 1; j < 6; j++) s -= M[i][j] * x0[j];
            x0[i] = s / M[i][i];
        }

        double nx0 = 0.0, nx = 0.0;
        float xf[6];
        for (int i = 0; i < 6; i++) {
            xf[i] = ws[i];
            nx0 += x0[i] * x0[i];
            nx  += (double)xf[i] * (double)xf[i];
        }
        nx0 = sqrt(nx0); nx = sqrt(nx);
        bool convold = (ws[6] != 0.f);
        bool c2 = convold || (new_cost < 1e-3) || (nx0 < 1e-8 * (1e-8 + nx));
        float xn[6];
        for (int i = 0; i < 6; i++)
            xn[i] = c2 ? xf[i] : (float)((double)xf[i] - x0[i]);
        for (int i = 0; i < 6; i++) ws[i] = xn[i];
        ws[6] = c2 ? 1.f : 0.f;
        if (!convold) ws[7] = (float)new_cost;

        float T[16];
        exp_se3_f32(xn, T);
        ws[8]  = T[0]; ws[9]  = T[1]; ws[10] = T[2];
        ws[11] = T[4]; ws[12] = T[5]; ws[13] = T[6];
        ws[14] = T[8]; ws[15] = T[9]; ws[16] = T[10];
        ws[17] = T[3]; ws[18] = T[7]; ws[19] = T[11];

        if (final_iter) {
            for (int i = 0; i < 16; i++) out[i] = T[i];
            out[16] = ws[7];
        }
    }
}

extern "C" void kernel_launch(void* const* d_in, const int* in_sizes, int n_in,
                              void* d_out, int out_size, void* d_ws, size_t ws_size,
                              hipStream_t stream) {
    const float* depth_ref      = (const float*)d_in[0];
    const float* normals_ref    = (const float*)d_in[1];
    const float* gray_ref       = (const float*)d_in[2];
    const float* gray_target    = (const float*)d_in[3];
    const float* points_target  = (const float*)d_in[4];
    const float* normals_target = (const float*)d_in[5];
    const float* K              = (const float*)d_in[6];
    float* ws  = (float*)d_ws;
    float* out = (float*)d_out;

    hipLaunchKernelGGL(init_state, dim3(1), dim3(64), 0, stream, ws);
    for (int it = 0; it < 20; ++it) {
        hipLaunchKernelGGL(map_reduce, dim3(MB), dim3(TPB), 0, stream,
                           depth_ref, normals_ref, gray_ref, gray_target,
                           points_target, normals_target, K, ws);
        hipLaunchKernelGGL(solve_update, dim3(1), dim3(TPB), 0, stream,
                           ws, out, (it == 19) ? 1 : 0);
    }
}